// Round 4
// baseline (586.546 us; speedup 1.0000x reference)
//
#include <hip/hip_runtime.h>
#include <hip/hip_cooperative_groups.h>
#include <cstdint>
#include <cstddef>

namespace cg = cooperative_groups;

#define NC     4096   // row length
#define NTHR   256
#define TGT_BLK 2048  // 8 blocks/CU on 256 CUs
#define LROWS  4      // rows cached in LDS per block

static __device__ __forceinline__ float waveReduceMax(float v) {
    #pragma unroll
    for (int off = 32; off > 0; off >>= 1)
        v = fmaxf(v, __shfl_down(v, off, 64));
    return v;
}
static __device__ __forceinline__ float waveReduceSum(float v) {
    #pragma unroll
    for (int off = 32; off > 0; off >>= 1)
        v += __shfl_down(v, off, 64);
    return v;
}

// returns block max broadcast to all threads (reads sred after barrier)
__device__ __forceinline__ float blockMax(float v, float* sred, int tid) {
    v = waveReduceMax(v);
    int lane = tid & 63, wid = tid >> 6;
    if (lane == 0) sred[wid] = v;
    __syncthreads();
    return fmaxf(fmaxf(sred[0], sred[1]), fmaxf(sred[2], sred[3]));
}

__device__ __forceinline__ void rowStatCompute(float Ex, float Ex2,
                                               float* mu_o, float* inv_o) {
    float mu  = Ex * (1.f / NC);
    float var = __fsub_rn(Ex2 * (1.f / NC), __fmul_rn(mu, mu));
    float var_f = fminf(fmaxf(rintf(var), 1.f), 65535.f);
    int vi = (int)var_f;
    int msb = min(31 - __clz(vi), 15);
    const float lut[16] = {65535.f, 46341.f, 32768.f, 23170.f, 16384.f, 11585.f,
                           8192.f, 5793.f, 4096.f, 2896.f, 2048.f, 1448.f,
                           1024.f, 724.f, 512.f, 362.f};
    *mu_o  = mu;
    *inv_o = lut[msb] * (1.f / 65536.f);
}

// ---------------- fused persistent cooperative kernel ----------------
// 8 blocks/CU (launch_bounds caps VGPR<=64), int8 staging in LDS.
__global__ __launch_bounds__(NTHR, 8) void k_fused(
    const float* __restrict__ x,
    const float* __restrict__ gamma,
    const float* __restrict__ beta,
    float* __restrict__ out,
    float* __restrict__ partA,      // [gridDim.x]
    float* __restrict__ partY,      // [gridDim.x]
    float2* __restrict__ row_stats, // [rows] (overflow rows only)
    int* __restrict__ xi8,          // overflow rows only
    int rows)
{
    cg::grid_group grid = cg::this_grid();
    const int tid = threadIdx.x;
    const int bid = blockIdx.x;
    const int nb  = gridDim.x;
    const int lane = tid & 63, wid = tid >> 6;

    __shared__ int    s_q[LROWS][NC / 4];   // 16 KB packed int8
    __shared__ float2 s_st[LROWS];          // per-row mu, inv_std
    __shared__ float  sred[8];
    __shared__ float  sbc[2];

    // ---- Phase A: absmax(x) over this block's rows; 16 independent loads
    float m = 0.f;
    for (int row = bid; row < rows; row += nb) {
        const float4* xr = (const float4*)(x + (size_t)row * NC);
        #pragma unroll
        for (int k = 0; k < 4; ++k) {
            float4 v = xr[tid + k * NTHR];
            m = fmaxf(fmaxf(fabsf(v.x), fabsf(v.y)),
                      fmaxf(fmaxf(fabsf(v.z), fabsf(v.w)), m));
        }
    }
    float bm = blockMax(m, sred, tid);
    if (tid == 0) partA[bid] = bm;
    grid.sync();

    // all blocks reduce all partials (max is order-independent, exact)
    float pm = 0.f;
    for (int i = tid; i < nb; i += NTHR) pm = fmaxf(pm, partA[i]);
    pm = blockMax(pm, sred, tid);
    const float scale_in = pm * (1.f / 127.f);
    const float r_in = 1.f / scale_in;

    // ---- Phase B: quantize -> LDS int8, row stats, running |y| max
    const float4* g4 = (const float4*)gamma;
    const float4* b4 = (const float4*)beta;
    float ym = 0.f;
    int r = 0;
    for (int row = bid; row < rows; row += nb, ++r) {
        __syncthreads();   // guard sred/sbc reuse
        const float4* xr = (const float4*)(x + (size_t)row * NC);
        float4 v[4];
        #pragma unroll
        for (int k = 0; k < 4; ++k) v[k] = xr[tid + k * NTHR];

        int pack[4];
        float ex = 0.f, ex2 = 0.f;
        #pragma unroll
        for (int k = 0; k < 4; ++k) {
            const float* pv = (const float*)&v[k];
            int pk = 0;
            #pragma unroll
            for (int j = 0; j < 4; ++j) {
                float xi = fminf(fmaxf(rintf(pv[j] * r_in), -127.f), 127.f);
                int ii = (int)xi;
                pk |= (ii & 255) << (8 * j);
                float q = xi * scale_in;
                ex += q;
                float aq = fabsf(q);
                bool hi = aq >= 64.f;                       // floor(aq/64) >= 1
                int idx = hi ? min((int)(aq * 0.0625f), 15) // clip(floor(aq/16),0,15)
                             : (((int)(aq * 0.5f)) & 15);   // mod(floor(aq/2),16)
                float sq = (float)(idx * idx);              // SQUARE_LUT
                ex2 += hi ? sq * 256.f : sq * 16.f;         // sq_decomp * 2^(2*ALPHA)
            }
            pack[k] = pk;
        }
        if (r < LROWS) {
            #pragma unroll
            for (int k = 0; k < 4; ++k) s_q[r][tid + k * NTHR] = pack[k];
        } else {
            int* wr = xi8 + (size_t)row * (NC / 4);
            #pragma unroll
            for (int k = 0; k < 4; ++k) wr[tid + k * NTHR] = pack[k];
        }

        ex  = waveReduceSum(ex);
        ex2 = waveReduceSum(ex2);
        if (lane == 0) { sred[wid] = ex; sred[4 + wid] = ex2; }
        __syncthreads();
        if (tid == 0) {
            float Ex  = (sred[0] + sred[1]) + (sred[2] + sred[3]);
            float Ex2 = (sred[4] + sred[5]) + (sred[6] + sred[7]);
            float mu, inv;
            rowStatCompute(Ex, Ex2, &mu, &inv);
            if (r < LROWS) s_st[r] = make_float2(mu, inv);
            else           row_stats[row] = make_float2(mu, inv);
            sbc[0] = mu; sbc[1] = inv;
        }
        __syncthreads();
        const float mu = sbc[0], inv = sbc[1];
        #pragma unroll
        for (int k = 0; k < 4; ++k) {
            float4 g = g4[tid + k * NTHR];
            float4 b = b4[tid + k * NTHR];
            const float* pg = (const float*)&g;
            const float* pb = (const float*)&b;
            int pk = pack[k];
            #pragma unroll
            for (int j = 0; j < 4; ++j) {
                int ii = (pk << (24 - 8 * j)) >> 24;        // sign-extend byte j
                float q = (float)ii * scale_in;
                float y = (q - mu) * inv * pg[j] + pb[j];
                ym = fmaxf(ym, fabsf(y));
            }
        }
    }
    __syncthreads();
    float bym = blockMax(ym, sred, tid);
    if (tid == 0) partY[bid] = bym;
    grid.sync();

    float py = 0.f;
    for (int i = tid; i < nb; i += NTHR) py = fmaxf(py, partY[i]);
    py = blockMax(py, sred, tid);
    const float scale_out = py * (1.f / 127.f);
    const float r_out = 1.f / scale_out;

    // ---- Phase C: finalize from LDS int8
    r = 0;
    for (int row = bid; row < rows; row += nb, ++r) {
        float2 st = (r < LROWS) ? s_st[r] : row_stats[row];
        const float mu = st.x, inv = st.y;
        float4* outr = (float4*)(out + (size_t)row * NC);
        #pragma unroll
        for (int k = 0; k < 4; ++k) {
            int pk = (r < LROWS) ? s_q[r][tid + k * NTHR]
                                 : xi8[(size_t)row * (NC / 4) + tid + k * NTHR];
            float4 g = g4[tid + k * NTHR];
            float4 b = b4[tid + k * NTHR];
            float4 o;
            const float* pg = (const float*)&g;
            const float* pb = (const float*)&b;
            float* po = (float*)&o;
            #pragma unroll
            for (int j = 0; j < 4; ++j) {
                int ii = (pk << (24 - 8 * j)) >> 24;
                float q = (float)ii * scale_in;
                float y = (q - mu) * inv * pg[j] + pb[j];
                float yi = fminf(fmaxf(rintf(y * r_out), -127.f), 127.f);
                po[j] = yi * scale_out;
            }
            outr[tid + k * NTHR] = o;
        }
    }
}

// ---------------- fallback path (non-cooperative), round-2 proven ----------------
__global__ __launch_bounds__(256) void k_absmax(const float* __restrict__ x,
                                                unsigned int* __restrict__ amax_bits,
                                                int n4) {
    int tid = blockIdx.x * blockDim.x + threadIdx.x;
    int stride = gridDim.x * blockDim.x;
    const float4* x4 = (const float4*)x;
    float m = 0.f;
    for (int i = tid; i < n4; i += stride) {
        float4 v = x4[i];
        m = fmaxf(m, fmaxf(fmaxf(fabsf(v.x), fabsf(v.y)),
                           fmaxf(fabsf(v.z), fabsf(v.w))));
    }
    __shared__ float sred[8];
    float b = blockMax(m, sred, threadIdx.x);
    if (threadIdx.x == 0) atomicMax(amax_bits, __float_as_uint(b));
}

__global__ __launch_bounds__(256) void k_rowstats(
    const float* __restrict__ x, const float* __restrict__ gamma,
    const float* __restrict__ beta, const unsigned int* __restrict__ amax_x_bits,
    unsigned int* __restrict__ amax_y_bits, float2* __restrict__ row_stats,
    int* __restrict__ xi8)
{
    const int row = blockIdx.x;
    const float scale_in = __uint_as_float(*amax_x_bits) * (1.0f / 127.0f);
    const float r_in = 1.0f / scale_in;
    const float4* xr = (const float4*)(x + (size_t)row * NC);
    const float4* g4 = (const float4*)gamma;
    const float4* b4 = (const float4*)beta;
    int pack[4];
    float ex = 0.f, ex2 = 0.f;
    #pragma unroll
    for (int k = 0; k < 4; ++k) {
        float4 v = xr[threadIdx.x + k * 256];
        const float* pv = (const float*)&v;
        int pk = 0;
        #pragma unroll
        for (int j = 0; j < 4; ++j) {
            float xi = fminf(fmaxf(rintf(pv[j] * r_in), -127.f), 127.f);
            int ii = (int)xi;
            pk |= (ii & 255) << (8 * j);
            float q = xi * scale_in;
            ex += q;
            float aq = fabsf(q);
            bool hi = aq >= 64.f;
            int idx = hi ? min((int)(aq * 0.0625f), 15) : (((int)(aq * 0.5f)) & 15);
            float sq = (float)(idx * idx);
            ex2 += hi ? sq * 256.f : sq * 16.f;
        }
        pack[k] = pk;
    }
    int* wr = xi8 + (size_t)row * (NC / 4);
    #pragma unroll
    for (int k = 0; k < 4; ++k) wr[threadIdx.x + k * 256] = pack[k];
    ex  = waveReduceSum(ex);
    ex2 = waveReduceSum(ex2);
    __shared__ float sred[8];
    __shared__ float sbc[2];
    int lane = threadIdx.x & 63, wid = threadIdx.x >> 6;
    if (lane == 0) { sred[wid] = ex; sred[4 + wid] = ex2; }
    __syncthreads();
    if (threadIdx.x == 0) {
        float Ex  = (sred[0] + sred[1]) + (sred[2] + sred[3]);
        float Ex2 = (sred[4] + sred[5]) + (sred[6] + sred[7]);
        float mu, inv;
        rowStatCompute(Ex, Ex2, &mu, &inv);
        sbc[0] = mu; sbc[1] = inv;
        row_stats[row] = make_float2(mu, inv);
    }
    __syncthreads();
    const float mu = sbc[0], inv = sbc[1];
    float ym = 0.f;
    #pragma unroll
    for (int k = 0; k < 4; ++k) {
        float4 g = g4[threadIdx.x + k * 256];
        float4 b = b4[threadIdx.x + k * 256];
        const float* pg = (const float*)&g;
        const float* pb = (const float*)&b;
        int pk = pack[k];
        #pragma unroll
        for (int j = 0; j < 4; ++j) {
            int ii = (pk << (24 - 8 * j)) >> 24;
            float q = (float)ii * scale_in;
            float y = (q - mu) * inv * pg[j] + pb[j];
            ym = fmaxf(ym, fabsf(y));
        }
    }
    __syncthreads();
    float b = blockMax(ym, sred, threadIdx.x);
    if (threadIdx.x == 0) atomicMax(amax_y_bits, __float_as_uint(b));
}

__global__ __launch_bounds__(256) void k_finalize_i8(
    const int* __restrict__ xi8, const float* __restrict__ gamma,
    const float* __restrict__ beta, const unsigned int* __restrict__ amax_x_bits,
    const unsigned int* __restrict__ amax_y_bits,
    const float2* __restrict__ row_stats, float* __restrict__ out)
{
    const int row = blockIdx.x;
    const float scale_in  = __uint_as_float(*amax_x_bits) * (1.0f / 127.0f);
    const float scale_out = __uint_as_float(*amax_y_bits) * (1.0f / 127.0f);
    const float r_out = 1.0f / scale_out;
    const float2 st = row_stats[row];
    const float mu = st.x, inv = st.y;
    const int* xr = xi8 + (size_t)row * (NC / 4);
    float4* outr = (float4*)(out + (size_t)row * NC);
    const float4* g4 = (const float4*)gamma;
    const float4* b4 = (const float4*)beta;
    #pragma unroll
    for (int k = 0; k < 4; ++k) {
        int pk = xr[threadIdx.x + k * 256];
        float4 g = g4[threadIdx.x + k * 256];
        float4 b = b4[threadIdx.x + k * 256];
        float4 o;
        const float* pg = (const float*)&g;
        const float* pb = (const float*)&b;
        float* po = (float*)&o;
        #pragma unroll
        for (int j = 0; j < 4; ++j) {
            int ii = (pk << (24 - 8 * j)) >> 24;
            float q = (float)ii * scale_in;
            float y = (q - mu) * inv * pg[j] + pb[j];
            float yi = fminf(fmaxf(rintf(y * r_out), -127.f), 127.f);
            po[j] = yi * scale_out;
        }
        outr[threadIdx.x + k * 256] = o;
    }
}

extern "C" void kernel_launch(void* const* d_in, const int* in_sizes, int n_in,
                              void* d_out, int out_size, void* d_ws, size_t ws_size,
                              hipStream_t stream) {
    const float* x     = (const float*)d_in[0];
    const float* gamma = (const float*)d_in[1];
    const float* beta  = (const float*)d_in[2];
    float* out = (float*)d_out;

    const int n    = in_sizes[0];
    const int rows = n / NC;
    const int n4   = n / 4;

    // ws layout: partA[TGT_BLK] | partY[TGT_BLK] | row_stats[rows] | xi8[n bytes]
    float*  partA = (float*)d_ws;
    float*  partY = partA + TGT_BLK;
    float2* row_stats = (float2*)((char*)d_ws + 2 * TGT_BLK * sizeof(float));
    size_t i8_off = (2 * TGT_BLK * sizeof(float) + (size_t)rows * 8 + 255) & ~(size_t)255;
    int* xi8 = (int*)((char*)d_ws + i8_off);
    bool ws_full = (ws_size >= i8_off + (size_t)n);
    bool ws_part = (ws_size >= i8_off);   // partials + row_stats only

    int occ = 0;
    hipError_t e = hipOccupancyMaxActiveBlocksPerMultiprocessor(&occ, k_fused, NTHR, 0);
    int nblk = 0;
    if (e == hipSuccess && occ > 0) nblk = min(TGT_BLK, occ * 256);

    bool launched = false;
    if (nblk >= 256) {
        int rpb = (rows + nblk - 1) / nblk;
        bool needs_overflow = rpb > LROWS;
        if ((!needs_overflow && ws_part) || (needs_overflow && ws_full)) {
            int rows_v = rows;
            void* args[] = {(void*)&x, (void*)&gamma, (void*)&beta, (void*)&out,
                            (void*)&partA, (void*)&partY, (void*)&row_stats,
                            (void*)&xi8, (void*)&rows_v};
            hipError_t le = hipLaunchCooperativeKernel((const void*)k_fused, dim3(nblk),
                                                       dim3(NTHR), args, 0, stream);
            launched = (le == hipSuccess);
        }
    }

    if (!launched) {
        unsigned int* amax_x = (unsigned int*)d_ws;
        unsigned int* amax_y = amax_x + 1;
        float2* rs2 = (float2*)((char*)d_ws + 1024);
        size_t off2 = (1024 + (size_t)rows * 8 + 255) & ~(size_t)255;
        int* xi8b = (int*)((char*)d_ws + off2);
        hipMemsetAsync(d_ws, 0, 1024, stream);
        k_absmax<<<2048, 256, 0, stream>>>(x, amax_x, n4);
        k_rowstats<<<rows, 256, 0, stream>>>(x, gamma, beta, amax_x, amax_y, rs2, xi8b);
        k_finalize_i8<<<rows, 256, 0, stream>>>(xi8b, gamma, beta, amax_x, amax_y, rs2, out);
    }
}

// Round 5
// 294.165 us; speedup vs baseline: 1.9939x; 1.9939x over previous
//
#include <hip/hip_runtime.h>
#include <cstdint>
#include <cstddef>

#define NC    4096   // row length
#define NTHR  256
#define R4    4      // rows per block in stats/finalize
#define NBUCK 256    // y-absmax buckets (== NTHR)

typedef float v4f __attribute__((ext_vector_type(4)));

static __device__ __forceinline__ float waveReduceMax(float v) {
    #pragma unroll
    for (int off = 32; off > 0; off >>= 1)
        v = fmaxf(v, __shfl_down(v, off, 64));
    return v;
}
static __device__ __forceinline__ float waveReduceSum(float v) {
    #pragma unroll
    for (int off = 32; off > 0; off >>= 1)
        v += __shfl_down(v, off, 64);
    return v;
}

// block max broadcast (4 waves of 64)
__device__ __forceinline__ float blockMax(float v, float* s4, int tid) {
    v = waveReduceMax(v);
    int lane = tid & 63, wid = tid >> 6;
    if (lane == 0) s4[wid] = v;
    __syncthreads();
    return fmaxf(fmaxf(s4[0], s4[1]), fmaxf(s4[2], s4[3]));
}

__device__ __forceinline__ void rowStatCompute(float Ex, float Ex2,
                                               float* mu_o, float* inv_o) {
    float mu  = Ex * (1.f / NC);
    float var = __fsub_rn(Ex2 * (1.f / NC), __fmul_rn(mu, mu));
    float var_f = fminf(fmaxf(rintf(var), 1.f), 65535.f);
    int vi = (int)var_f;
    int msb = min(31 - __clz(vi), 15);
    const float lut[16] = {65535.f, 46341.f, 32768.f, 23170.f, 16384.f, 11585.f,
                           8192.f, 5793.f, 4096.f, 2896.f, 2048.f, 1448.f,
                           1024.f, 724.f, 512.f, 362.f};
    *mu_o  = mu;
    *inv_o = lut[msb] * (1.f / 65536.f);
}

// ---- Pass 1: global absmax(x); 8 loads in flight per wave, 1 atomic/block
__global__ __launch_bounds__(NTHR) void k_absmax(const float* __restrict__ x,
                                                 unsigned int* __restrict__ amax_bits,
                                                 int n4) {
    const float4* x4 = (const float4*)x;
    int t = blockIdx.x * NTHR + threadIdx.x;
    int S = gridDim.x * NTHR;
    float m = 0.f;
    int full = (n4 / (S * 8)) * (S * 8);
    for (int base = t; base < full; base += S * 8) {
        float4 v[8];
        #pragma unroll
        for (int u = 0; u < 8; ++u) v[u] = x4[base + u * S];
        #pragma unroll
        for (int u = 0; u < 8; ++u)
            m = fmaxf(m, fmaxf(fmaxf(fabsf(v[u].x), fabsf(v[u].y)),
                               fmaxf(fabsf(v[u].z), fabsf(v[u].w))));
    }
    for (int i = full + t; i < n4; i += S) {
        float4 v = x4[i];
        m = fmaxf(m, fmaxf(fmaxf(fabsf(v.x), fabsf(v.y)),
                           fmaxf(fabsf(v.z), fabsf(v.w))));
    }
    __shared__ float s4[4];
    float b = blockMax(m, s4, threadIdx.x);
    if (threadIdx.x == 0) atomicMax(amax_bits, __float_as_uint(b));
}

// ---- Pass 2: 4 rows/block. gamma/beta held in regs; one reduce barrier for
//      all 4 rows; int8 staged to ws; |y| max -> bucketed atomic.
__global__ __launch_bounds__(NTHR) void k_rowstats4(
    const float* __restrict__ x,
    const float* __restrict__ gamma,
    const float* __restrict__ beta,
    const unsigned int* __restrict__ amax_x_bits,
    unsigned int* __restrict__ ybuck,      // [NBUCK]
    float2* __restrict__ row_stats,
    int* __restrict__ xi8)
{
    const int tid = threadIdx.x;
    const int base_row = blockIdx.x * R4;
    const float scale_in = __uint_as_float(*amax_x_bits) * (1.0f / 127.0f);
    const float r_in = 1.0f / scale_in;

    const float4* g4 = (const float4*)gamma;
    const float4* b4 = (const float4*)beta;
    float4 gh[4], bh[4];
    #pragma unroll
    for (int k = 0; k < 4; ++k) { gh[k] = g4[tid + k * NTHR]; bh[k] = b4[tid + k * NTHR]; }

    float exr[R4], ex2r[R4];
    int pack[R4][4];
    #pragma unroll
    for (int r = 0; r < R4; ++r) {
        const int row = base_row + r;
        const float4* xr = (const float4*)(x + (size_t)row * NC);
        float4 v[4];
        #pragma unroll
        for (int k = 0; k < 4; ++k) v[k] = xr[tid + k * NTHR];

        float ex = 0.f, ex2 = 0.f;
        #pragma unroll
        for (int k = 0; k < 4; ++k) {
            const float* pv = (const float*)&v[k];
            int pk = 0;
            #pragma unroll
            for (int j = 0; j < 4; ++j) {
                float xi = fminf(fmaxf(rintf(pv[j] * r_in), -127.f), 127.f);
                int ii = (int)xi;
                pk |= (ii & 255) << (8 * j);
                float q = xi * scale_in;
                ex += q;
                float aq = fabsf(q);
                bool hi = aq >= 64.f;                       // floor(aq/64) >= 1
                int idx = hi ? min((int)(aq * 0.0625f), 15) // clip(floor(aq/16),0,15)
                             : (((int)(aq * 0.5f)) & 15);   // mod(floor(aq/2),16)
                float sq = (float)(idx * idx);              // SQUARE_LUT
                ex2 += hi ? sq * 256.f : sq * 16.f;         // sq_decomp * 2^(2*ALPHA)
            }
            pack[r][k] = pk;
        }
        exr[r] = ex; ex2r[r] = ex2;
        int* wr = xi8 + (size_t)row * (NC / 4);
        #pragma unroll
        for (int k = 0; k < 4; ++k) wr[tid + k * NTHR] = pack[r][k];
    }

    // one reduction for all 4 rows
    #pragma unroll
    for (int r = 0; r < R4; ++r) {
        exr[r]  = waveReduceSum(exr[r]);
        ex2r[r] = waveReduceSum(ex2r[r]);
    }
    __shared__ float sred[4][8];          // [wave][ex0..3, ex2_0..3]
    __shared__ float2 s_st[R4];
    const int lane = tid & 63, wid = tid >> 6;
    if (lane == 0) {
        #pragma unroll
        for (int r = 0; r < R4; ++r) { sred[wid][r] = exr[r]; sred[wid][4 + r] = ex2r[r]; }
    }
    __syncthreads();
    if (tid < R4) {                        // thread r computes row r's stats
        float Ex  = (sred[0][tid] + sred[1][tid]) + (sred[2][tid] + sred[3][tid]);
        float Ex2 = (sred[0][4 + tid] + sred[1][4 + tid]) + (sred[2][4 + tid] + sred[3][4 + tid]);
        float mu, inv;
        rowStatCompute(Ex, Ex2, &mu, &inv);
        s_st[tid] = make_float2(mu, inv);
        row_stats[base_row + tid] = make_float2(mu, inv);
    }
    __syncthreads();

    float ym = 0.f;
    #pragma unroll
    for (int r = 0; r < R4; ++r) {
        const float mu = s_st[r].x, inv = s_st[r].y;
        #pragma unroll
        for (int k = 0; k < 4; ++k) {
            const float* pg = (const float*)&gh[k];
            const float* pb = (const float*)&bh[k];
            int pk = pack[r][k];
            #pragma unroll
            for (int j = 0; j < 4; ++j) {
                int ii = (pk << (24 - 8 * j)) >> 24;        // sign-extend byte j
                float q = (float)ii * scale_in;
                float y = (q - mu) * inv * pg[j] + pb[j];
                ym = fmaxf(ym, fabsf(y));
            }
        }
    }
    __shared__ float smax[4];
    float bym = blockMax(ym, smax, tid);
    if (tid == 0) atomicMax(&ybuck[blockIdx.x & (NBUCK - 1)], __float_as_uint(bym));
}

// ---- Pass 3: 4 rows/block; bucket-reduce scale_out; nontemporal out stores
__global__ __launch_bounds__(NTHR) void k_finalize4(
    const int* __restrict__ xi8,
    const float* __restrict__ gamma,
    const float* __restrict__ beta,
    const unsigned int* __restrict__ amax_x_bits,
    const unsigned int* __restrict__ ybuck,
    const float2* __restrict__ row_stats,
    float* __restrict__ out)
{
    const int tid = threadIdx.x;
    const int base_row = blockIdx.x * R4;
    const float scale_in = __uint_as_float(*amax_x_bits) * (1.0f / 127.0f);

    float by = __uint_as_float(ybuck[tid]);    // NBUCK == NTHR
    __shared__ float s4[4];
    float pym = blockMax(by, s4, tid);
    const float scale_out = pym * (1.f / 127.f);
    const float r_out = 1.f / scale_out;

    const float4* g4 = (const float4*)gamma;
    const float4* b4 = (const float4*)beta;
    float4 gh[4], bh[4];
    #pragma unroll
    for (int k = 0; k < 4; ++k) { gh[k] = g4[tid + k * NTHR]; bh[k] = b4[tid + k * NTHR]; }

    #pragma unroll
    for (int r = 0; r < R4; ++r) {
        const int row = base_row + r;
        const int* rd = xi8 + (size_t)row * (NC / 4);
        int pk[4];
        #pragma unroll
        for (int k = 0; k < 4; ++k) pk[k] = rd[tid + k * NTHR];
        const float2 st = row_stats[row];
        const float mu = st.x, inv = st.y;
        float* outr = out + (size_t)row * NC;
        #pragma unroll
        for (int k = 0; k < 4; ++k) {
            const float* pg = (const float*)&gh[k];
            const float* pb = (const float*)&bh[k];
            v4f o;
            #pragma unroll
            for (int j = 0; j < 4; ++j) {
                int ii = (pk[k] << (24 - 8 * j)) >> 24;
                float q = (float)ii * scale_in;
                float y = (q - mu) * inv * pg[j] + pb[j];
                float yi = fminf(fmaxf(rintf(y * r_out), -127.f), 127.f);
                o[j] = yi * scale_out;
            }
            __builtin_nontemporal_store(o, (v4f*)(outr + (tid + k * NTHR) * 4));
        }
    }
}

// ---------------- fallback (round-2 proven, one row/block) ----------------
__global__ __launch_bounds__(256) void k_rowstats_fb(
    const float* __restrict__ x, const float* __restrict__ gamma,
    const float* __restrict__ beta, const unsigned int* __restrict__ amax_x_bits,
    unsigned int* __restrict__ amax_y_bits, float2* __restrict__ row_stats,
    int* __restrict__ xi8)
{
    const int row = blockIdx.x;
    const float scale_in = __uint_as_float(*amax_x_bits) * (1.0f / 127.0f);
    const float r_in = 1.0f / scale_in;
    const float4* xr = (const float4*)(x + (size_t)row * NC);
    const float4* g4 = (const float4*)gamma;
    const float4* b4 = (const float4*)beta;
    int pack[4];
    float ex = 0.f, ex2 = 0.f;
    #pragma unroll
    for (int k = 0; k < 4; ++k) {
        float4 v = xr[threadIdx.x + k * 256];
        const float* pv = (const float*)&v;
        int pk = 0;
        #pragma unroll
        for (int j = 0; j < 4; ++j) {
            float xi = fminf(fmaxf(rintf(pv[j] * r_in), -127.f), 127.f);
            int ii = (int)xi;
            pk |= (ii & 255) << (8 * j);
            float q = xi * scale_in;
            ex += q;
            float aq = fabsf(q);
            bool hi = aq >= 64.f;
            int idx = hi ? min((int)(aq * 0.0625f), 15) : (((int)(aq * 0.5f)) & 15);
            float sq = (float)(idx * idx);
            ex2 += hi ? sq * 256.f : sq * 16.f;
        }
        pack[k] = pk;
    }
    int* wr = xi8 + (size_t)row * (NC / 4);
    #pragma unroll
    for (int k = 0; k < 4; ++k) wr[threadIdx.x + k * 256] = pack[k];
    ex  = waveReduceSum(ex);
    ex2 = waveReduceSum(ex2);
    __shared__ float sred[8];
    __shared__ float sbc[2];
    int lane = threadIdx.x & 63, wid = threadIdx.x >> 6;
    if (lane == 0) { sred[wid] = ex; sred[4 + wid] = ex2; }
    __syncthreads();
    if (threadIdx.x == 0) {
        float Ex  = (sred[0] + sred[1]) + (sred[2] + sred[3]);
        float Ex2 = (sred[4] + sred[5]) + (sred[6] + sred[7]);
        float mu, inv;
        rowStatCompute(Ex, Ex2, &mu, &inv);
        sbc[0] = mu; sbc[1] = inv;
        row_stats[row] = make_float2(mu, inv);
    }
    __syncthreads();
    const float mu = sbc[0], inv = sbc[1];
    float ym = 0.f;
    #pragma unroll
    for (int k = 0; k < 4; ++k) {
        float4 g = g4[threadIdx.x + k * 256];
        float4 b = b4[threadIdx.x + k * 256];
        const float* pg = (const float*)&g;
        const float* pb = (const float*)&b;
        int pk = pack[k];
        #pragma unroll
        for (int j = 0; j < 4; ++j) {
            int ii = (pk << (24 - 8 * j)) >> 24;
            float q = (float)ii * scale_in;
            float y = (q - mu) * inv * pg[j] + pb[j];
            ym = fmaxf(ym, fabsf(y));
        }
    }
    __syncthreads();
    __shared__ float smax[4];
    float b = blockMax(ym, smax, threadIdx.x);
    if (threadIdx.x == 0) atomicMax(amax_y_bits, __float_as_uint(b));
}

__global__ __launch_bounds__(256) void k_finalize_fb(
    const int* __restrict__ xi8, const float* __restrict__ gamma,
    const float* __restrict__ beta, const unsigned int* __restrict__ amax_x_bits,
    const unsigned int* __restrict__ amax_y_bits,
    const float2* __restrict__ row_stats, float* __restrict__ out)
{
    const int row = blockIdx.x;
    const float scale_in  = __uint_as_float(*amax_x_bits) * (1.0f / 127.0f);
    const float scale_out = __uint_as_float(*amax_y_bits) * (1.0f / 127.0f);
    const float r_out = 1.0f / scale_out;
    const float2 st = row_stats[row];
    const float mu = st.x, inv = st.y;
    const int* xr = xi8 + (size_t)row * (NC / 4);
    float4* outr = (float4*)(out + (size_t)row * NC);
    const float4* g4 = (const float4*)gamma;
    const float4* b4 = (const float4*)beta;
    #pragma unroll
    for (int k = 0; k < 4; ++k) {
        int pk = xr[threadIdx.x + k * 256];
        float4 g = g4[threadIdx.x + k * 256];
        float4 b = b4[threadIdx.x + k * 256];
        float4 o;
        const float* pg = (const float*)&g;
        const float* pb = (const float*)&b;
        float* po = (float*)&o;
        #pragma unroll
        for (int j = 0; j < 4; ++j) {
            int ii = (pk << (24 - 8 * j)) >> 24;
            float q = (float)ii * scale_in;
            float y = (q - mu) * inv * pg[j] + pb[j];
            float yi = fminf(fmaxf(rintf(y * r_out), -127.f), 127.f);
            po[j] = yi * scale_out;
        }
        outr[threadIdx.x + k * 256] = o;
    }
}

extern "C" void kernel_launch(void* const* d_in, const int* in_sizes, int n_in,
                              void* d_out, int out_size, void* d_ws, size_t ws_size,
                              hipStream_t stream) {
    const float* x     = (const float*)d_in[0];
    const float* gamma = (const float*)d_in[1];
    const float* beta  = (const float*)d_in[2];
    float* out = (float*)d_out;

    const int n    = in_sizes[0];
    const int rows = n / NC;
    const int n4   = n / 4;

    // ws layout: [0]=amax_x, [8]=amax_y(fb), [1024..2047]=ybuck[256],
    //            [4096..)=row_stats[rows], then xi8 (256-aligned)
    unsigned int* amax_x = (unsigned int*)d_ws;
    unsigned int* amax_y = (unsigned int*)((char*)d_ws + 8);
    unsigned int* ybuck  = (unsigned int*)((char*)d_ws + 1024);
    float2* row_stats    = (float2*)((char*)d_ws + 4096);
    size_t i8_off = (4096 + (size_t)rows * 8 + 255) & ~(size_t)255;
    int* xi8 = (int*)((char*)d_ws + i8_off);
    bool ws_ok = (ws_size >= i8_off + (size_t)n);

    hipMemsetAsync(d_ws, 0, 4096, stream);   // amax words + buckets

    k_absmax<<<512, NTHR, 0, stream>>>(x, amax_x, n4);

    if (ws_ok && (rows % R4) == 0) {
        k_rowstats4<<<rows / R4, NTHR, 0, stream>>>(x, gamma, beta, amax_x,
                                                    ybuck, row_stats, xi8);
        k_finalize4<<<rows / R4, NTHR, 0, stream>>>(xi8, gamma, beta, amax_x,
                                                    ybuck, row_stats, out);
    } else {
        k_rowstats_fb<<<rows, NTHR, 0, stream>>>(x, gamma, beta, amax_x, amax_y,
                                                 row_stats, xi8);
        k_finalize_fb<<<rows, NTHR, 0, stream>>>(xi8, gamma, beta, amax_x, amax_y,
                                                 row_stats, out);
    }
}

// Round 6
// 292.194 us; speedup vs baseline: 2.0074x; 1.0067x over previous
//
#include <hip/hip_runtime.h>
#include <cstdint>
#include <cstddef>

#define NC    4096   // row length
#define NTHR  256
#define NBUCK 256    // y-absmax buckets (== NTHR)

typedef float v4f __attribute__((ext_vector_type(4)));

static __device__ __forceinline__ float waveReduceMax(float v) {
    #pragma unroll
    for (int off = 32; off > 0; off >>= 1)
        v = fmaxf(v, __shfl_down(v, off, 64));
    return v;
}

// block max broadcast (4 waves of 64)
__device__ __forceinline__ float blockMax(float v, float* s4, int tid) {
    v = waveReduceMax(v);
    int lane = tid & 63, wid = tid >> 6;
    if (lane == 0) s4[wid] = v;
    __syncthreads();
    return fmaxf(fmaxf(s4[0], s4[1]), fmaxf(s4[2], s4[3]));
}

__device__ __forceinline__ void rowStatCompute(float Ex, float Ex2,
                                               float* mu_o, float* inv_o) {
    float mu  = Ex * (1.f / NC);
    float var = __fsub_rn(Ex2 * (1.f / NC), __fmul_rn(mu, mu));
    float var_f = fminf(fmaxf(rintf(var), 1.f), 65535.f);
    int vi = (int)var_f;
    int msb = min(31 - __clz(vi), 15);
    const float lut[16] = {65535.f, 46341.f, 32768.f, 23170.f, 16384.f, 11585.f,
                           8192.f, 5793.f, 4096.f, 2896.f, 2048.f, 1448.f,
                           1024.f, 724.f, 512.f, 362.f};
    *mu_o  = mu;
    *inv_o = lut[msb] * (1.f / 65536.f);
}

// ---- Pass 1: global absmax(x); 8 loads in flight per thread
__global__ __launch_bounds__(NTHR) void k_absmax(const float* __restrict__ x,
                                                 unsigned int* __restrict__ amax_bits,
                                                 int n4) {
    const float4* x4 = (const float4*)x;
    int t = blockIdx.x * NTHR + threadIdx.x;
    int S = gridDim.x * NTHR;
    float m = 0.f;
    int full = (n4 / (S * 8)) * (S * 8);
    for (int base = t; base < full; base += S * 8) {
        float4 v[8];
        #pragma unroll
        for (int u = 0; u < 8; ++u) v[u] = x4[base + u * S];
        #pragma unroll
        for (int u = 0; u < 8; ++u)
            m = fmaxf(m, fmaxf(fmaxf(fabsf(v[u].x), fabsf(v[u].y)),
                               fmaxf(fabsf(v[u].z), fabsf(v[u].w))));
    }
    for (int i = full + t; i < n4; i += S) {
        float4 v = x4[i];
        m = fmaxf(m, fmaxf(fmaxf(fabsf(v.x), fabsf(v.y)),
                           fmaxf(fabsf(v.z), fabsf(v.w))));
    }
    __shared__ float s4[4];
    float b = blockMax(m, s4, threadIdx.x);
    if (threadIdx.x == 0) atomicMax(amax_bits, __float_as_uint(b));
}

// ---- Pass 2: WAVE per row. No LDS, no barriers. Lane handles cols lane+64e.
__global__ __launch_bounds__(NTHR) void k_rowstats_w(
    const float* __restrict__ x,
    const float* __restrict__ gamma,
    const float* __restrict__ beta,
    const unsigned int* __restrict__ amax_x_bits,
    unsigned int* __restrict__ ybuck,      // [NBUCK]
    float2* __restrict__ row_stats,
    int* __restrict__ xi8)
{
    const int tid  = threadIdx.x;
    const int lane = tid & 63;
    const int row  = blockIdx.x * 4 + (tid >> 6);   // one wave per row
    const float scale_in = __uint_as_float(*amax_x_bits) * (1.0f / 127.0f);
    const float r_in = 1.0f / scale_in;

    const float4* xr = (const float4*)(x + (size_t)row * NC);
    int pack[16];
    float ex = 0.f, ex2 = 0.f;
    #pragma unroll
    for (int e = 0; e < 16; e += 8) {
        float4 v[8];
        #pragma unroll
        for (int u = 0; u < 8; ++u) v[u] = xr[lane + 64 * (e + u)];
        #pragma unroll
        for (int u = 0; u < 8; ++u) {
            const float* pv = (const float*)&v[u];
            int pk = 0;
            #pragma unroll
            for (int j = 0; j < 4; ++j) {
                float xi = fminf(fmaxf(rintf(pv[j] * r_in), -127.f), 127.f);
                int ii = (int)xi;
                pk |= (ii & 255) << (8 * j);
                float q = xi * scale_in;
                ex += q;
                float aq = fabsf(q);
                bool hi = aq >= 64.f;                       // floor(aq/64) >= 1
                int idx = hi ? min((int)(aq * 0.0625f), 15) // clip(floor(aq/16),0,15)
                             : (((int)(aq * 0.5f)) & 15);   // mod(floor(aq/2),16)
                float sq = (float)(idx * idx);              // SQUARE_LUT
                ex2 += hi ? sq * 256.f : sq * 16.f;         // sq_decomp * 2^(2*ALPHA)
            }
            pack[e + u] = pk;
        }
    }

    // stage packed int8 (coalesced)
    int* wr = xi8 + (size_t)row * (NC / 4);
    #pragma unroll
    for (int e = 0; e < 16; ++e) wr[lane + 64 * e] = pack[e];

    // wave-level reduction, then broadcast lane 0's value (deterministic,
    // bit-identical to what finalize reads from row_stats)
    #pragma unroll
    for (int off = 1; off < 64; off <<= 1) {
        ex  += __shfl_xor(ex,  off, 64);
        ex2 += __shfl_xor(ex2, off, 64);
    }
    ex  = __shfl(ex,  0, 64);
    ex2 = __shfl(ex2, 0, 64);
    float mu, inv;
    rowStatCompute(ex, ex2, &mu, &inv);
    if (lane == 0) row_stats[row] = make_float2(mu, inv);

    // row |y| max: re-stream gamma/beta (L1/L2-resident, 32 KB total)
    const float4* g4 = (const float4*)gamma;
    const float4* b4 = (const float4*)beta;
    float ym = 0.f;
    #pragma unroll
    for (int e = 0; e < 16; e += 4) {
        float4 g[4], b[4];
        #pragma unroll
        for (int u = 0; u < 4; ++u) {
            g[u] = g4[lane + 64 * (e + u)];
            b[u] = b4[lane + 64 * (e + u)];
        }
        #pragma unroll
        for (int u = 0; u < 4; ++u) {
            const float* pg = (const float*)&g[u];
            const float* pb = (const float*)&b[u];
            int pk = pack[e + u];
            #pragma unroll
            for (int j = 0; j < 4; ++j) {
                int ii = (pk << (24 - 8 * j)) >> 24;        // sign-extend byte j
                float q = (float)ii * scale_in;
                float y = (q - mu) * inv * pg[j] + pb[j];
                ym = fmaxf(ym, fabsf(y));
            }
        }
    }
    #pragma unroll
    for (int off = 1; off < 64; off <<= 1)
        ym = fmaxf(ym, __shfl_xor(ym, off, 64));
    if (lane == 0) atomicMax(&ybuck[row & (NBUCK - 1)], __float_as_uint(ym));
}

// ---- Pass 3: WAVE per row; one barrier for bucket reduce; NT stores
__global__ __launch_bounds__(NTHR) void k_finalize_w(
    const int* __restrict__ xi8,
    const float* __restrict__ gamma,
    const float* __restrict__ beta,
    const unsigned int* __restrict__ amax_x_bits,
    const unsigned int* __restrict__ ybuck,
    const float2* __restrict__ row_stats,
    float* __restrict__ out)
{
    const int tid  = threadIdx.x;
    const int lane = tid & 63;
    const int row  = blockIdx.x * 4 + (tid >> 6);
    const float scale_in = __uint_as_float(*amax_x_bits) * (1.0f / 127.0f);

    float by = __uint_as_float(ybuck[tid]);    // NBUCK == NTHR
    __shared__ float s4[4];
    float pym = blockMax(by, s4, tid);
    const float scale_out = pym * (1.f / 127.f);
    const float r_out = 1.f / scale_out;

    const float2 st = row_stats[row];
    const float mu = st.x, inv = st.y;
    const int* rd = xi8 + (size_t)row * (NC / 4);
    float* outr = out + (size_t)row * NC;
    const float4* g4 = (const float4*)gamma;
    const float4* b4 = (const float4*)beta;

    #pragma unroll
    for (int e = 0; e < 16; e += 4) {
        int pk[4];
        float4 g[4], b[4];
        #pragma unroll
        for (int u = 0; u < 4; ++u) {
            pk[u] = rd[lane + 64 * (e + u)];
            g[u]  = g4[lane + 64 * (e + u)];
            b[u]  = b4[lane + 64 * (e + u)];
        }
        #pragma unroll
        for (int u = 0; u < 4; ++u) {
            const float* pg = (const float*)&g[u];
            const float* pb = (const float*)&b[u];
            v4f o;
            #pragma unroll
            for (int j = 0; j < 4; ++j) {
                int ii = (pk[u] << (24 - 8 * j)) >> 24;
                float q = (float)ii * scale_in;
                float y = (q - mu) * inv * pg[j] + pb[j];
                float yi = fminf(fmaxf(rintf(y * r_out), -127.f), 127.f);
                o[j] = yi * scale_out;
            }
            __builtin_nontemporal_store(o, (v4f*)(outr + (lane + 64 * (e + u)) * 4));
        }
    }
}

// ---------------- fallback (round-2 proven, one row/block) ----------------
__global__ __launch_bounds__(256) void k_rowstats_fb(
    const float* __restrict__ x, const float* __restrict__ gamma,
    const float* __restrict__ beta, const unsigned int* __restrict__ amax_x_bits,
    unsigned int* __restrict__ amax_y_bits, float2* __restrict__ row_stats,
    int* __restrict__ xi8)
{
    const int row = blockIdx.x;
    const float scale_in = __uint_as_float(*amax_x_bits) * (1.0f / 127.0f);
    const float r_in = 1.0f / scale_in;
    const float4* xr = (const float4*)(x + (size_t)row * NC);
    const float4* g4 = (const float4*)gamma;
    const float4* b4 = (const float4*)beta;
    int pack[4];
    float ex = 0.f, ex2 = 0.f;
    #pragma unroll
    for (int k = 0; k < 4; ++k) {
        float4 v = xr[threadIdx.x + k * 256];
        const float* pv = (const float*)&v;
        int pk = 0;
        #pragma unroll
        for (int j = 0; j < 4; ++j) {
            float xi = fminf(fmaxf(rintf(pv[j] * r_in), -127.f), 127.f);
            int ii = (int)xi;
            pk |= (ii & 255) << (8 * j);
            float q = xi * scale_in;
            ex += q;
            float aq = fabsf(q);
            bool hi = aq >= 64.f;
            int idx = hi ? min((int)(aq * 0.0625f), 15) : (((int)(aq * 0.5f)) & 15);
            float sq = (float)(idx * idx);
            ex2 += hi ? sq * 256.f : sq * 16.f;
        }
        pack[k] = pk;
    }
    int* wr = xi8 + (size_t)row * (NC / 4);
    #pragma unroll
    for (int k = 0; k < 4; ++k) wr[threadIdx.x + k * 256] = pack[k];
    #pragma unroll
    for (int off = 1; off < 64; off <<= 1) {
        ex  += __shfl_xor(ex,  off, 64);
        ex2 += __shfl_xor(ex2, off, 64);
    }
    __shared__ float sred[8];
    __shared__ float sbc[2];
    int lane = threadIdx.x & 63, wid = threadIdx.x >> 6;
    if (lane == 0) { sred[wid] = ex; sred[4 + wid] = ex2; }
    __syncthreads();
    if (threadIdx.x == 0) {
        float Ex  = (sred[0] + sred[1]) + (sred[2] + sred[3]);
        float Ex2 = (sred[4] + sred[5]) + (sred[6] + sred[7]);
        float mu, inv;
        rowStatCompute(Ex, Ex2, &mu, &inv);
        sbc[0] = mu; sbc[1] = inv;
        row_stats[row] = make_float2(mu, inv);
    }
    __syncthreads();
    const float mu = sbc[0], inv = sbc[1];
    float ym = 0.f;
    #pragma unroll
    for (int k = 0; k < 4; ++k) {
        float4 g = g4[threadIdx.x + k * 256];
        float4 b = b4[threadIdx.x + k * 256];
        const float* pg = (const float*)&g;
        const float* pb = (const float*)&b;
        int pk = pack[k];
        #pragma unroll
        for (int j = 0; j < 4; ++j) {
            int ii = (pk << (24 - 8 * j)) >> 24;
            float q = (float)ii * scale_in;
            float y = (q - mu) * inv * pg[j] + pb[j];
            ym = fmaxf(ym, fabsf(y));
        }
    }
    __syncthreads();
    __shared__ float smax[4];
    float b = blockMax(ym, smax, threadIdx.x);
    if (threadIdx.x == 0) atomicMax(amax_y_bits, __float_as_uint(b));
}

__global__ __launch_bounds__(256) void k_finalize_fb(
    const int* __restrict__ xi8, const float* __restrict__ gamma,
    const float* __restrict__ beta, const unsigned int* __restrict__ amax_x_bits,
    const unsigned int* __restrict__ amax_y_bits,
    const float2* __restrict__ row_stats, float* __restrict__ out)
{
    const int row = blockIdx.x;
    const float scale_in  = __uint_as_float(*amax_x_bits) * (1.0f / 127.0f);
    const float scale_out = __uint_as_float(*amax_y_bits) * (1.0f / 127.0f);
    const float r_out = 1.0f / scale_out;
    const float2 st = row_stats[row];
    const float mu = st.x, inv = st.y;
    const int* xr = xi8 + (size_t)row * (NC / 4);
    float4* outr = (float4*)(out + (size_t)row * NC);
    const float4* g4 = (const float4*)gamma;
    const float4* b4 = (const float4*)beta;
    #pragma unroll
    for (int k = 0; k < 4; ++k) {
        int pk = xr[threadIdx.x + k * 256];
        float4 g = g4[threadIdx.x + k * 256];
        float4 b = b4[threadIdx.x + k * 256];
        float4 o;
        const float* pg = (const float*)&g;
        const float* pb = (const float*)&b;
        float* po = (float*)&o;
        #pragma unroll
        for (int j = 0; j < 4; ++j) {
            int ii = (pk << (24 - 8 * j)) >> 24;
            float q = (float)ii * scale_in;
            float y = (q - mu) * inv * pg[j] + pb[j];
            float yi = fminf(fmaxf(rintf(y * r_out), -127.f), 127.f);
            po[j] = yi * scale_out;
        }
        outr[threadIdx.x + k * 256] = o;
    }
}

extern "C" void kernel_launch(void* const* d_in, const int* in_sizes, int n_in,
                              void* d_out, int out_size, void* d_ws, size_t ws_size,
                              hipStream_t stream) {
    const float* x     = (const float*)d_in[0];
    const float* gamma = (const float*)d_in[1];
    const float* beta  = (const float*)d_in[2];
    float* out = (float*)d_out;

    const int n    = in_sizes[0];
    const int rows = n / NC;
    const int n4   = n / 4;

    // ws layout: [0]=amax_x, [8]=amax_y(fb), [1024..2047]=ybuck[256],
    //            [4096..)=row_stats[rows], then xi8 (256-aligned)
    unsigned int* amax_x = (unsigned int*)d_ws;
    unsigned int* amax_y = (unsigned int*)((char*)d_ws + 8);
    unsigned int* ybuck  = (unsigned int*)((char*)d_ws + 1024);
    float2* row_stats    = (float2*)((char*)d_ws + 4096);
    size_t i8_off = (4096 + (size_t)rows * 8 + 255) & ~(size_t)255;
    int* xi8 = (int*)((char*)d_ws + i8_off);
    bool ws_ok = (ws_size >= i8_off + (size_t)n);

    hipMemsetAsync(d_ws, 0, 4096, stream);   // amax words + buckets

    k_absmax<<<512, NTHR, 0, stream>>>(x, amax_x, n4);

    if (ws_ok && (rows % 4) == 0) {
        k_rowstats_w<<<rows / 4, NTHR, 0, stream>>>(x, gamma, beta, amax_x,
                                                    ybuck, row_stats, xi8);
        k_finalize_w<<<rows / 4, NTHR, 0, stream>>>(xi8, gamma, beta, amax_x,
                                                    ybuck, row_stats, out);
    } else {
        k_rowstats_fb<<<rows, NTHR, 0, stream>>>(x, gamma, beta, amax_x, amax_y,
                                                 row_stats, xi8);
        k_finalize_fb<<<rows, NTHR, 0, stream>>>(xi8, gamma, beta, amax_x, amax_y,
                                                 row_stats, out);
    }
}